// Round 19
// baseline (72.243 us; speedup 1.0000x reference)
//
#include <hip/hip_runtime.h>
#include <hip/hip_bf16.h>
#include <math.h>

#define NPTS 131072
#define DIM 32
#define MCL 256
#define NSTEP 18           // symmetric packing: 1 sq + 15 pair + 1 pair/lin + 1 lin/pad
#define BPTS 128           // points per block
#define THREADS 256

typedef __attribute__((ext_vector_type(8))) _Float16 f16x8;   // MFMA A/B fragment
typedef __attribute__((ext_vector_type(2))) _Float16 h2v;     // packed f16 pair
typedef __attribute__((ext_vector_type(2))) unsigned u2v;     // 2 dwords (4 f16)
typedef __attribute__((ext_vector_type(4))) float f32x4;

__device__ __forceinline__ short f2h(float f) {
    _Float16 h = (_Float16)f;
    union { _Float16 h; short s; } X; X.h = h; return X.s;
}

__device__ __forceinline__ void glds16(const void* g, void* l) {
    __builtin_amdgcn_global_load_lds(
        (const __attribute__((address_space(1))) unsigned int*)g,
        (__attribute__((address_space(3))) unsigned int*)l, 16, 0, 0);
}

// ---------------------------------------------------------------------------
// prep (256 threads/cluster): symmetric-packed G (f16):
//  step 0           : c = E[k][k]                (squares; E = LL^T - I)
//  steps 1..15      : c = 2*E[k][(k+s)&31]       (pairs, circular diff s)
//  step 16, k<16    : c = 2*E[k][k+16]           (diff-16 pairs)
//  step 16, k>=16   : c = -2*Ac[k-16]            (linear)
//  step 17, k<16    : c = -2*Ac[k+16]            (linear)
//  step 17, k>=16   : c = 0                      (pad)
// G addr (shorts): s*8192 + (m>>4)*512 + (k>>3)*128 + (m&15)*8 + (k&7)
// logdet: register GE on wave 0 (col-per-lane, unrolled, no pivot).
// ---------------------------------------------------------------------------
__global__ __launch_bounds__(256) void gmm_prep(
    const float* __restrict__ center,
    const float* __restrict__ L,
    const float* __restrict__ weight,
    short* __restrict__ G,
    float* __restrict__ cst)
{
    const int m = blockIdx.x;
    const int t = threadIdx.x;
    __shared__ float Ls[DIM][DIM + 1];
    __shared__ float As[DIM][DIM + 1];
    __shared__ float Acs[DIM];
    __shared__ float red[DIM];

    const float* Lm = L + m * DIM * DIM;
    for (int k = t; k < DIM * DIM; k += 256)
        Ls[k >> 5][k & 31] = Lm[k];
    __syncthreads();

    // A = L L^T  (4 elems/thread)
    for (int idx = t; idx < DIM * DIM; idx += 256) {
        const int j = idx >> 5, l = idx & 31;
        float a = 0.f;
        #pragma unroll
        for (int d = 0; d < DIM; ++d) a = fmaf(Ls[j][d], Ls[l][d], a);
        As[j][l] = a;
    }
    __syncthreads();

    if (t < DIM) {
        float a = 0.f;
        #pragma unroll
        for (int l = 0; l < DIM; ++l) a = fmaf(As[t][l], center[m * DIM + l], a);
        Acs[t] = a;
        red[t] = a * center[m * DIM + t];
    }
    __syncthreads();

    const int mt = m >> 4, ml = m & 15;
    for (int idx = t; idx < NSTEP * 32; idx += 256) {
        const int s = idx >> 5, k = idx & 31;
        float c;
        if (s == 0)       c = As[k][k] - 1.0f;
        else if (s <= 15) c = 2.0f * As[k][(k + s) & 31];
        else if (s == 16) c = (k < 16) ? 2.0f * As[k][k + 16] : -2.0f * Acs[k - 16];
        else              c = (k < 16) ? -2.0f * Acs[k + 16] : 0.0f;
        G[s * 8192 + mt * 512 + (k >> 3) * 128 + ml * 8 + (k & 7)] = f2h(c);
    }

    if (t < 64) {
        // register GE, no pivot: lane j owns column j.
        float logdet = 0.f;
        if (t < DIM) {
            float col[DIM];
            #pragma unroll
            for (int r2 = 0; r2 < DIM; ++r2) col[r2] = Ls[r2][t];
            float prodabs = 1.0f;
            #pragma unroll
            for (int k = 0; k < DIM; ++k) {
                const float pv  = __shfl(col[k], k, 64);
                const float rpv = 1.0f / pv;
                const float cjk = col[k];
                #pragma unroll
                for (int t2 = k + 1; t2 < DIM; ++t2) {
                    const float f = __shfl(col[t2], k, 64) * rpv;
                    col[t2] = fmaf(-f, cjk, col[t2]);
                }
                prodabs *= fabsf(pv);
            }
            logdet = logf(prodabs);
        }

        float wsp = 0.f;
        for (int j = t; j < MCL; j += 64) wsp += fabsf(weight[j]);
        #pragma unroll
        for (int d2 = 1; d2 < 64; d2 <<= 1) wsp += __shfl_xor(wsp, d2, 64);

        if (t == 0) {
            float t3 = 0.f;
            #pragma unroll
            for (int j = 0; j < DIM; ++j) t3 += red[j];
            cst[m] = logf(fabsf(weight[m])) - logf(wsp) + logdet - 0.5f * t3;
        }
    }
}

// ---------------------------------------------------------------------------
// main kernel helpers. With the dual-shifted LDS copy, every window read has
// an EVEN sub-offset (0 or 2) -> wpair never needs alignbit.
// ---------------------------------------------------------------------------
template<int J>
__device__ __forceinline__ unsigned wword(const u2v b0, const u2v b1, const u2v b2) {
    if constexpr (J < 2)      return b0[J];
    else if constexpr (J < 4) return b1[J - 2];
    else                      return b2[J - 4];
}

template<int OFF2, int Q>
__device__ __forceinline__ h2v wpair(const u2v b0, const u2v b1, const u2v b2) {
    static_assert((OFF2 & 1) == 0, "odd offsets eliminated by XhO copy");
    constexpr int wj = (OFF2 + 2 * Q) >> 1;
    union { unsigned u; h2v h; } X; X.u = wword<wj>(b0, b1, b2); return X.h;
}

template<int S, int Q, int OFF2>
__device__ __forceinline__ h2v mkpair(const h2v (&xp)[4], int kg,
                                      const u2v b0, const u2v b1, const u2v b2) {
    if constexpr (S == 0) {
        return xp[Q] * xp[Q];                    // squares: window == own slice
    } else {
        const h2v wp = wpair<OFF2, Q>(b0, b1, b2);
        if constexpr (S == 16) {
            return (kg < 2) ? (h2v)(xp[Q] * wp) : wp;   // pairs | linear
        } else if constexpr (S == 17) {
            const h2v z = { (_Float16)0.f, (_Float16)0.f };
            return (kg < 2) ? wp : z;                    // linear | pad
        } else {
            return xp[Q] * wp;
        }
    }
}

// ---------------------------------------------------------------------------
// main: R17 engine (128 pts x 256 cl, 4 waves, wave tile 64x128, acc[4][8],
// 2 waves/SIMD, f16 A-gen, dual-shifted Xh) + R19 change: B goes back
// through LDS BROADCAST (R6's path) instead of per-wave global loads.
// Rationale: R17's true-VALU is negligible (VALUBusy==MfmaUtil); the stall
// is B-traffic: 64 KB/CU/step of per-wave global loads (~1000 cyc at
// ~64 B/cyc L1) vs 620-cyc MFMA demand. LDS staging loads each B byte ONCE
// per block (glds16, 4/wave/step = 32 KB/CU/step global, ~500 cyc) and
// serves waves from LDS (64 KB/CU/step at 256 B/clk ~ 250 cyc, 120-cyc
// latency). Double-buffered, R6's proven fused vmcnt(0)+barrier per step;
// 2 independent blocks/CU desync the drains.
// ---------------------------------------------------------------------------
template<int S>
__device__ __forceinline__ void stage(const short* __restrict__ G,
                                      short (&Bb)[2][8192], int w, int lane)
{
    constexpr int b = S & 1;
    const short* gs = G + (size_t)S * 8192 + w * 2048 + lane * 8;
    #pragma unroll
    for (int q = 0; q < 4; ++q)
        glds16(gs + q * 512, &Bb[b][w * 2048 + q * 512]);
}

template<int S>
__device__ __forceinline__ void k_step(
    const short* __restrict__ G,
    short (&Bb)[2][8192],
    const short* __restrict__ Xh,
    const short* __restrict__ XhO,
    const int (&rowh)[4],
    const h2v (&xp)[4][4],
    f32x4 (&acc)[4][8],
    int w, int lane, int kg, int wc)
{
    constexpr int cb = S & 1;
    // issue next-tile staging FIRST; lands under this step's MFMA burst
    if constexpr (S + 1 < NSTEP) stage<S + 1>(G, Bb, w, lane);

    constexpr int shv  = (S == 17) ? 16 : S;
    constexpr bool odd = (shv & 1) != 0;
    constexpr int sh2  = odd ? (shv - 1) : shv;     // shift within chosen copy
    constexpr int off2 = sh2 & 3;                   // 0 or 2 -> no alignbit
    const int bq = ((kg * 8 + sh2) & 31) & ~3;      // aligned 4-half base

    f16x8 af[4];
    #pragma unroll
    for (int i = 0; i < 4; ++i) {
        u2v b0 = {}, b1 = {}, b2 = {};
        if constexpr (S != 0) {
            const short* xr = (odd ? XhO : Xh) + rowh[i] + bq;
            b0 = *(const u2v*)(xr);
            b1 = *(const u2v*)(xr + 4);
            if constexpr (off2 != 0) b2 = *(const u2v*)(xr + 8);
        }
        union { f16x8 v; h2v p[4]; } U;
        U.p[0] = mkpair<S, 0, off2>(xp[i], kg, b0, b1, b2);
        U.p[1] = mkpair<S, 1, off2>(xp[i], kg, b0, b1, b2);
        U.p[2] = mkpair<S, 2, off2>(xp[i], kg, b0, b1, b2);
        U.p[3] = mkpair<S, 3, off2>(xp[i], kg, b0, b1, b2);
        af[i] = U.v;
    }

    // B fragments from LDS (conflict-free lane-contiguous b128)
    f16x8 bf[8];
    #pragma unroll
    for (int j = 0; j < 8; ++j)
        bf[j] = *(const f16x8*)&Bb[cb][(wc * 8 + j) * 512 + lane * 8];

    #pragma unroll
    for (int i = 0; i < 4; ++i)
        #pragma unroll
        for (int j = 0; j < 8; ++j)
            acc[i][j] = __builtin_amdgcn_mfma_f32_16x16x32_f16(
                af[i], bf[j], acc[i][j], 0, 0, 0);

    // staging for S+1 had the whole step to land; drain + barrier orders
    // the buffer swap (next step's stage<S+2> overwrites Bb[cb]).
    if constexpr (S + 1 < NSTEP)
        asm volatile("s_waitcnt vmcnt(0) lgkmcnt(0)\n\ts_barrier" ::: "memory");
}

template<int S>
__device__ __forceinline__ void k_loop(
    const short* __restrict__ G, short (&Bb)[2][8192],
    const short* __restrict__ Xh, const short* __restrict__ XhO,
    const int (&rowh)[4], const h2v (&xp)[4][4],
    f32x4 (&acc)[4][8], int w, int lane, int kg, int wc)
{
    k_step<S>(G, Bb, Xh, XhO, rowh, xp, acc, w, lane, kg, wc);
    if constexpr (S + 1 < NSTEP)
        k_loop<S + 1>(G, Bb, Xh, XhO, rowh, xp, acc, w, lane, kg, wc);
}

__global__ __launch_bounds__(THREADS, 2) void gmm_mfma(
    const float* __restrict__ X,
    const short* __restrict__ G,
    const float* __restrict__ cstw,
    const float* __restrict__ thr,
    float* __restrict__ out)
{
    __shared__ __attribute__((aligned(16))) short Bb[2][8192];    // 32 KB
    __shared__ __attribute__((aligned(16))) short Xh[BPTS * 44];  // 11.3 KB
    __shared__ __attribute__((aligned(16))) short XhO[BPTS * 44]; // 11.3 KB
    __shared__ float nrm_s[BPTS];
    __shared__ float cst_s[MCL];
    __shared__ float lse_m[BPTS];
    __shared__ float lse_d[BPTS];

    const int tid  = threadIdx.x;
    const int lane = tid & 63;
    const int w    = tid >> 6;     // wave 0..3
    const int wr   = w & 1;        // row half: 64 points
    const int wc   = w >> 1;       // col half: 128 clusters
    const int r    = lane & 15;
    const int kg   = lane >> 4;
    const int P0   = blockIdx.x * BPTS;

    // stage B step-0 (async)
    stage<0>(G, Bb, w, lane);

    // resident x-slices -> packed f16 pairs (4 row-fragments of 16)
    int rowh[4];
    h2v xp[4][4];
    #pragma unroll
    for (int i = 0; i < 4; ++i) {
        const int row = wr * 64 + i * 16 + r;
        rowh[i] = row * 44;
        const float4* xg = reinterpret_cast<const float4*>(
            X + (size_t)(P0 + row) * DIM + kg * 8);
        const float4 a = xg[0], b = xg[1];
        xp[i][0] = h2v{ (_Float16)a.x, (_Float16)a.y };
        xp[i][1] = h2v{ (_Float16)a.z, (_Float16)a.w };
        xp[i][2] = h2v{ (_Float16)b.x, (_Float16)b.y };
        xp[i][3] = h2v{ (_Float16)b.z, (_Float16)b.w };
    }

    // stage Xh (x[k]) and XhO (x[(k+1)&31]), both +8 dup for wrap; row norms
    {
        const int p = tid >> 1, hf = tid & 1;
        const float4* Xg = reinterpret_cast<const float4*>(
            X + (size_t)(P0 + p) * DIM + hf * 16);
        float part = 0.f;
        #pragma unroll
        for (int q = 0; q < 4; ++q) {
            const float4 v = Xg[q];
            const int kb = hf * 16 + 4 * q;
            const short h0 = f2h(v.x), h1 = f2h(v.y), h2 = f2h(v.z), h3 = f2h(v.w);
            Xh[p * 44 + kb + 0] = h0;
            Xh[p * 44 + kb + 1] = h1;
            Xh[p * 44 + kb + 2] = h2;
            Xh[p * 44 + kb + 3] = h3;
            if (!hf && q < 2) {
                Xh[p * 44 + 32 + kb + 0] = h0;
                Xh[p * 44 + 32 + kb + 1] = h1;
                Xh[p * 44 + 32 + kb + 2] = h2;
                Xh[p * 44 + 32 + kb + 3] = h3;
            }
            // XhO[i] = x[(i+1)&31]  ->  x[k] lands at i = (k-1)&31
            const int i0 = (kb - 1) & 31;
            XhO[p * 44 + i0] = h0;
            XhO[p * 44 + kb + 0] = h1;
            XhO[p * 44 + kb + 1] = h2;
            XhO[p * 44 + kb + 2] = h3;
            if (i0 < 8)       XhO[p * 44 + 32 + i0] = h0;
            if (kb + 0 < 8) { XhO[p * 44 + 32 + kb + 0] = h1; }
            if (kb + 1 < 8) { XhO[p * 44 + 32 + kb + 1] = h2; }
            if (kb + 2 < 8) { XhO[p * 44 + 32 + kb + 2] = h3; }
            part = fmaf(v.x, v.x, part); part = fmaf(v.y, v.y, part);
            part = fmaf(v.z, v.z, part); part = fmaf(v.w, v.w, part);
        }
        part += __shfl_xor(part, 1, 64);
        if (!hf) nrm_s[p] = part;
        cst_s[tid] = cstw[tid];
    }

    // Xh/XhO ds_writes drained + stage<0> landed; all waves proceed.
    asm volatile("s_waitcnt vmcnt(0) lgkmcnt(0)\n\ts_barrier" ::: "memory");

    f32x4 acc[4][8] = {};
    k_loop<0>(G, Bb, Xh, XhO, rowh, xp, acc, w, lane, kg, wc);

    // ---- epilogue: weighted LSE over this wave's 128 clusters.
    // Butterfly max first, one exp pass, butterfly add (R12 pattern).
    float cstr[8];
    #pragma unroll
    for (int j = 0; j < 8; ++j)
        cstr[j] = cst_s[wc * 128 + j * 16 + r];

    float mx[16], sm[16];
    #pragma unroll
    for (int i = 0; i < 4; ++i)
        #pragma unroll
        for (int rg = 0; rg < 4; ++rg) {
            const int sl = i * 4 + rg;
            float m_ = -1e30f;
            #pragma unroll
            for (int j = 0; j < 8; ++j)
                m_ = fmaxf(m_, fmaf(acc[i][j][rg], -0.5f, cstr[j]));
            #pragma unroll
            for (int d = 1; d < 16; d <<= 1)
                m_ = fmaxf(m_, __shfl_xor(m_, d, 64));
            float s_ = 0.f;
            #pragma unroll
            for (int j = 0; j < 8; ++j)
                s_ += __expf(fmaf(acc[i][j][rg], -0.5f, cstr[j]) - m_);
            #pragma unroll
            for (int d = 1; d < 16; d <<= 1)
                s_ += __shfl_xor(s_, d, 64);
            mx[sl] = m_; sm[sl] = s_;
        }

    // cross col-half merge via LDS
    if (wc == 0 && r == 0) {
        #pragma unroll
        for (int i = 0; i < 4; ++i)
            #pragma unroll
            for (int rg = 0; rg < 4; ++rg) {
                const int p2 = wr * 64 + i * 16 + kg * 4 + rg;
                lse_m[p2] = mx[i * 4 + rg];
                lse_d[p2] = sm[i * 4 + rg];
            }
    }
    __syncthreads();
    if (wc == 1 && r == 0) {
        const float thrv = thr[0];
        #pragma unroll
        for (int i = 0; i < 4; ++i)
            #pragma unroll
            for (int rg = 0; rg < 4; ++rg) {
                const int sl = i * 4 + rg;
                const int p2 = wr * 64 + i * 16 + kg * 4 + rg;
                const float om = lse_m[p2], os = lse_d[p2];
                const float nm = fmaxf(mx[sl], om);
                const float ss = sm[sl] * __expf(mx[sl] - nm) + os * __expf(om - nm);
                out[P0 + p2] = nm + __logf(ss) - 0.5f * nrm_s[p2] - thrv;
            }
    }
}

extern "C" void kernel_launch(void* const* d_in, const int* in_sizes, int n_in,
                              void* d_out, int out_size, void* d_ws, size_t ws_size,
                              hipStream_t stream)
{
    const float* X      = (const float*)d_in[0];
    const float* center = (const float*)d_in[1];
    const float* L      = (const float*)d_in[2];
    const float* weight = (const float*)d_in[3];
    const float* thr    = (const float*)d_in[4];
    float* out = (float*)d_out;

    // ws layout: cst [256] f32 | G [18*8192] f16-as-short (~296 KB)
    float* cst = (float*)d_ws;
    short* G   = (short*)((char*)d_ws + 1024);

    gmm_prep<<<MCL, 256, 0, stream>>>(center, L, weight, G, cst);
    gmm_mfma<<<NPTS / BPTS, THREADS, 0, stream>>>(X, G, cst, thr, out);
}

// Round 20
// 64.442 us; speedup vs baseline: 1.1210x; 1.1210x over previous
//
#include <hip/hip_runtime.h>
#include <hip/hip_bf16.h>
#include <math.h>

#define NPTS 131072
#define DIM 32
#define MCL 256
#define NSTEP 18           // symmetric packing: 1 sq + 15 pair + 1 pair/lin + 1 lin/pad
#define BPTS 128           // points per block
#define THREADS 256

typedef __attribute__((ext_vector_type(8))) _Float16 f16x8;   // MFMA A/B fragment
typedef __attribute__((ext_vector_type(2))) _Float16 h2v;     // packed f16 pair
typedef __attribute__((ext_vector_type(2))) unsigned u2v;     // 2 dwords (4 f16)
typedef __attribute__((ext_vector_type(4))) float f32x4;

__device__ __forceinline__ short f2h(float f) {
    _Float16 h = (_Float16)f;
    union { _Float16 h; short s; } X; X.h = h; return X.s;
}

// ---------------------------------------------------------------------------
// prep (256 threads/cluster): symmetric-packed G (f16):
//  step 0           : c = E[k][k]                (squares; E = LL^T - I)
//  steps 1..15      : c = 2*E[k][(k+s)&31]       (pairs, circular diff s)
//  step 16, k<16    : c = 2*E[k][k+16]           (diff-16 pairs)
//  step 16, k>=16   : c = -2*Ac[k-16]            (linear)
//  step 17, k<16    : c = -2*Ac[k+16]            (linear)
//  step 17, k>=16   : c = 0                      (pad)
// G addr (shorts): s*8192 + (m>>4)*512 + (k>>3)*128 + (m&15)*8 + (k&7)
// logdet: register GE on wave 0 (col-per-lane, unrolled, no pivot).
// ---------------------------------------------------------------------------
__global__ __launch_bounds__(256) void gmm_prep(
    const float* __restrict__ center,
    const float* __restrict__ L,
    const float* __restrict__ weight,
    short* __restrict__ G,
    float* __restrict__ cst)
{
    const int m = blockIdx.x;
    const int t = threadIdx.x;
    __shared__ float Ls[DIM][DIM + 1];
    __shared__ float As[DIM][DIM + 1];
    __shared__ float Acs[DIM];
    __shared__ float red[DIM];

    const float* Lm = L + m * DIM * DIM;
    for (int k = t; k < DIM * DIM; k += 256)
        Ls[k >> 5][k & 31] = Lm[k];
    __syncthreads();

    // A = L L^T  (4 elems/thread)
    for (int idx = t; idx < DIM * DIM; idx += 256) {
        const int j = idx >> 5, l = idx & 31;
        float a = 0.f;
        #pragma unroll
        for (int d = 0; d < DIM; ++d) a = fmaf(Ls[j][d], Ls[l][d], a);
        As[j][l] = a;
    }
    __syncthreads();

    if (t < DIM) {
        float a = 0.f;
        #pragma unroll
        for (int l = 0; l < DIM; ++l) a = fmaf(As[t][l], center[m * DIM + l], a);
        Acs[t] = a;
        red[t] = a * center[m * DIM + t];
    }
    __syncthreads();

    const int mt = m >> 4, ml = m & 15;
    for (int idx = t; idx < NSTEP * 32; idx += 256) {
        const int s = idx >> 5, k = idx & 31;
        float c;
        if (s == 0)       c = As[k][k] - 1.0f;
        else if (s <= 15) c = 2.0f * As[k][(k + s) & 31];
        else if (s == 16) c = (k < 16) ? 2.0f * As[k][k + 16] : -2.0f * Acs[k - 16];
        else              c = (k < 16) ? -2.0f * Acs[k + 16] : 0.0f;
        G[s * 8192 + mt * 512 + (k >> 3) * 128 + ml * 8 + (k & 7)] = f2h(c);
    }

    if (t < 64) {
        // register GE, no pivot: lane j owns column j.
        float logdet = 0.f;
        if (t < DIM) {
            float col[DIM];
            #pragma unroll
            for (int r2 = 0; r2 < DIM; ++r2) col[r2] = Ls[r2][t];
            float prodabs = 1.0f;
            #pragma unroll
            for (int k = 0; k < DIM; ++k) {
                const float pv  = __shfl(col[k], k, 64);
                const float rpv = 1.0f / pv;
                const float cjk = col[k];
                #pragma unroll
                for (int t2 = k + 1; t2 < DIM; ++t2) {
                    const float f = __shfl(col[t2], k, 64) * rpv;
                    col[t2] = fmaf(-f, cjk, col[t2]);
                }
                prodabs *= fabsf(pv);
            }
            logdet = logf(prodabs);
        }

        float wsp = 0.f;
        for (int j = t; j < MCL; j += 64) wsp += fabsf(weight[j]);
        #pragma unroll
        for (int d2 = 1; d2 < 64; d2 <<= 1) wsp += __shfl_xor(wsp, d2, 64);

        if (t == 0) {
            float t3 = 0.f;
            #pragma unroll
            for (int j = 0; j < DIM; ++j) t3 += red[j];
            cst[m] = logf(fabsf(weight[m])) - logf(wsp) + logdet - 0.5f * t3;
        }
    }
}

// ---------------------------------------------------------------------------
// main kernel helpers. With the dual-shifted LDS copy, every window read has
// an EVEN sub-offset (0 or 2) -> wpair never needs alignbit.
// ---------------------------------------------------------------------------
template<int J>
__device__ __forceinline__ unsigned wword(const u2v b0, const u2v b1, const u2v b2) {
    if constexpr (J < 2)      return b0[J];
    else if constexpr (J < 4) return b1[J - 2];
    else                      return b2[J - 4];
}

template<int OFF2, int Q>
__device__ __forceinline__ h2v wpair(const u2v b0, const u2v b1, const u2v b2) {
    static_assert((OFF2 & 1) == 0, "odd offsets eliminated by XhO copy");
    constexpr int wj = (OFF2 + 2 * Q) >> 1;
    union { unsigned u; h2v h; } X; X.u = wword<wj>(b0, b1, b2); return X.h;
}

template<int S, int Q, int OFF2>
__device__ __forceinline__ h2v mkpair(const h2v (&xp)[4], int kg,
                                      const u2v b0, const u2v b1, const u2v b2) {
    if constexpr (S == 0) {
        return xp[Q] * xp[Q];                    // squares: window == own slice
    } else {
        const h2v wp = wpair<OFF2, Q>(b0, b1, b2);
        if constexpr (S == 16) {
            return (kg < 2) ? (h2v)(xp[Q] * wp) : wp;   // pairs | linear
        } else if constexpr (S == 17) {
            const h2v z = { (_Float16)0.f, (_Float16)0.f };
            return (kg < 2) ? wp : z;                    // linear | pad
        } else {
            return xp[Q] * wp;
        }
    }
}

// ---------------------------------------------------------------------------
// main: R17 structure EXACTLY (block = 128 pts x 256 cl, 4 waves, wave tile
// 64x128, acc[4][8] = 128 AGPR, 2 waves/SIMD, reg-resident B from L2-hot G,
// j-outer bf refill, dual-shifted Xh) with ONE change vs R17:
// per-step fence mask 0 -> 0x104 = {SALU | DS_READ may cross}. Next step's
// window ds_reads (the ~120-cyc serial step-head) can hoist into this
// step's MFMA tail; VALU stays pinned so af live ranges don't extend
// (R18's spill came from VALU/ALU crossing: VGPR 124->128, WRITE 0.5->6MB).
// Tripwires: VGPR <= 126, WRITE_SIZE ~0.5 MB, else revert to R17.
// ---------------------------------------------------------------------------
template<int S>
__device__ __forceinline__ void k_step(
    const short* __restrict__ gw,      // G + wc*4096 + lane*8 (shorts)
    const short* __restrict__ Xh,
    const short* __restrict__ XhO,
    const int (&rowh)[4],
    const h2v (&xp)[4][4],
    f16x8 (&bf)[8],
    f32x4 (&acc)[4][8],
    int kg)
{
    constexpr int shv  = (S == 17) ? 16 : S;
    constexpr bool odd = (shv & 1) != 0;
    constexpr int sh2  = odd ? (shv - 1) : shv;     // shift within chosen copy
    constexpr int off2 = sh2 & 3;                   // 0 or 2 -> no alignbit
    const int bq = ((kg * 8 + sh2) & 31) & ~3;      // aligned 4-half base

    f16x8 af[4];
    #pragma unroll
    for (int i = 0; i < 4; ++i) {
        u2v b0 = {}, b1 = {}, b2 = {};
        if constexpr (S != 0) {
            const short* xr = (odd ? XhO : Xh) + rowh[i] + bq;
            b0 = *(const u2v*)(xr);
            b1 = *(const u2v*)(xr + 4);
            if constexpr (off2 != 0) b2 = *(const u2v*)(xr + 8);
        }
        union { f16x8 v; h2v p[4]; } U;
        U.p[0] = mkpair<S, 0, off2>(xp[i], kg, b0, b1, b2);
        U.p[1] = mkpair<S, 1, off2>(xp[i], kg, b0, b1, b2);
        U.p[2] = mkpair<S, 2, off2>(xp[i], kg, b0, b1, b2);
        U.p[3] = mkpair<S, 3, off2>(xp[i], kg, b0, b1, b2);
        af[i] = U.v;
    }

    // j-outer: all 4 readers of bf[j] run, then bf[j] refills for S+1 --
    // the j=0 load has 28 MFMAs of wall-time before its next use.
    #pragma unroll
    for (int j = 0; j < 8; ++j) {
        #pragma unroll
        for (int i = 0; i < 4; ++i)
            acc[i][j] = __builtin_amdgcn_mfma_f32_16x16x32_f16(
                af[i], bf[j], acc[i][j], 0, 0, 0);
        if constexpr (S + 1 < NSTEP)
            bf[j] = *(const f16x8*)(gw + (size_t)(S + 1) * 8192 + j * 512);
    }
    // fence: only SALU + DS_READ may cross (next step's window reads hoist
    // into this step's MFMA tail); VALU/VMEM/MFMA pinned (R18 lesson).
    __builtin_amdgcn_sched_barrier(0x104);
}

template<int S>
__device__ __forceinline__ void k_loop(
    const short* __restrict__ gw, const short* __restrict__ Xh,
    const short* __restrict__ XhO,
    const int (&rowh)[4], const h2v (&xp)[4][4],
    f16x8 (&bf)[8], f32x4 (&acc)[4][8], int kg)
{
    k_step<S>(gw, Xh, XhO, rowh, xp, bf, acc, kg);
    if constexpr (S + 1 < NSTEP)
        k_loop<S + 1>(gw, Xh, XhO, rowh, xp, bf, acc, kg);
}

__global__ __launch_bounds__(THREADS, 2) void gmm_mfma(
    const float* __restrict__ X,
    const short* __restrict__ G,
    const float* __restrict__ cstw,
    const float* __restrict__ thr,
    float* __restrict__ out)
{
    __shared__ __attribute__((aligned(16))) short Xh[BPTS * 44];  // 11.3 KB
    __shared__ __attribute__((aligned(16))) short XhO[BPTS * 44]; // 11.3 KB
    __shared__ float nrm_s[BPTS];
    __shared__ float cst_s[MCL];
    __shared__ float lse_m[BPTS];
    __shared__ float lse_d[BPTS];

    const int tid  = threadIdx.x;
    const int lane = tid & 63;
    const int w    = tid >> 6;     // wave 0..3
    const int wr   = w & 1;        // row half: 64 points
    const int wc   = w >> 1;       // col half: 128 clusters
    const int r    = lane & 15;
    const int kg   = lane >> 4;
    const int P0   = blockIdx.x * BPTS;

    // per-wave B pointer: cols wc*128.., this lane's 8 f16
    const short* gw = G + wc * 4096 + lane * 8;

    // resident x-slices -> packed f16 pairs (4 row-fragments of 16)
    int rowh[4];
    h2v xp[4][4];
    #pragma unroll
    for (int i = 0; i < 4; ++i) {
        const int row = wr * 64 + i * 16 + r;
        rowh[i] = row * 44;
        const float4* xg = reinterpret_cast<const float4*>(
            X + (size_t)(P0 + row) * DIM + kg * 8);
        const float4 a = xg[0], b = xg[1];
        xp[i][0] = h2v{ (_Float16)a.x, (_Float16)a.y };
        xp[i][1] = h2v{ (_Float16)a.z, (_Float16)a.w };
        xp[i][2] = h2v{ (_Float16)b.x, (_Float16)b.y };
        xp[i][3] = h2v{ (_Float16)b.z, (_Float16)b.w };
    }

    // stage Xh (x[k]) and XhO (x[(k+1)&31]), both +8 dup for wrap; row norms
    {
        const int p = tid >> 1, hf = tid & 1;
        const float4* Xg = reinterpret_cast<const float4*>(
            X + (size_t)(P0 + p) * DIM + hf * 16);
        float part = 0.f;
        #pragma unroll
        for (int q = 0; q < 4; ++q) {
            const float4 v = Xg[q];
            const int kb = hf * 16 + 4 * q;
            const short h0 = f2h(v.x), h1 = f2h(v.y), h2 = f2h(v.z), h3 = f2h(v.w);
            Xh[p * 44 + kb + 0] = h0;
            Xh[p * 44 + kb + 1] = h1;
            Xh[p * 44 + kb + 2] = h2;
            Xh[p * 44 + kb + 3] = h3;
            if (!hf && q < 2) {
                Xh[p * 44 + 32 + kb + 0] = h0;
                Xh[p * 44 + 32 + kb + 1] = h1;
                Xh[p * 44 + 32 + kb + 2] = h2;
                Xh[p * 44 + 32 + kb + 3] = h3;
            }
            // XhO[i] = x[(i+1)&31]  ->  x[k] lands at i = (k-1)&31
            const int i0 = (kb - 1) & 31;
            XhO[p * 44 + i0] = h0;
            XhO[p * 44 + kb + 0] = h1;
            XhO[p * 44 + kb + 1] = h2;
            XhO[p * 44 + kb + 2] = h3;
            if (i0 < 8)       XhO[p * 44 + 32 + i0] = h0;
            if (kb + 0 < 8) { XhO[p * 44 + 32 + kb + 0] = h1; }
            if (kb + 1 < 8) { XhO[p * 44 + 32 + kb + 1] = h2; }
            if (kb + 2 < 8) { XhO[p * 44 + 32 + kb + 2] = h3; }
            part = fmaf(v.x, v.x, part); part = fmaf(v.y, v.y, part);
            part = fmaf(v.z, v.z, part); part = fmaf(v.w, v.w, part);
        }
        part += __shfl_xor(part, 1, 64);
        if (!hf) nrm_s[p] = part;
        cst_s[tid] = cstw[tid];
    }

    // prologue: load step-0 B fragments
    f16x8 bf[8];
    #pragma unroll
    for (int j = 0; j < 8; ++j)
        bf[j] = *(const f16x8*)(gw + j * 512);

    __syncthreads();   // Xh/XhO/nrm/cst visible to all waves

    f32x4 acc[4][8] = {};
    k_loop<0>(gw, Xh, XhO, rowh, xp, bf, acc, kg);

    // ---- epilogue: weighted LSE over this wave's 128 clusters.
    // Butterfly max first, one exp pass, butterfly add (R12 pattern).
    float cstr[8];
    #pragma unroll
    for (int j = 0; j < 8; ++j)
        cstr[j] = cst_s[wc * 128 + j * 16 + r];

    float mx[16], sm[16];
    #pragma unroll
    for (int i = 0; i < 4; ++i)
        #pragma unroll
        for (int rg = 0; rg < 4; ++rg) {
            const int sl = i * 4 + rg;
            float m_ = -1e30f;
            #pragma unroll
            for (int j = 0; j < 8; ++j)
                m_ = fmaxf(m_, fmaf(acc[i][j][rg], -0.5f, cstr[j]));
            #pragma unroll
            for (int d = 1; d < 16; d <<= 1)
                m_ = fmaxf(m_, __shfl_xor(m_, d, 64));
            float s_ = 0.f;
            #pragma unroll
            for (int j = 0; j < 8; ++j)
                s_ += __expf(fmaf(acc[i][j][rg], -0.5f, cstr[j]) - m_);
            #pragma unroll
            for (int d = 1; d < 16; d <<= 1)
                s_ += __shfl_xor(s_, d, 64);
            mx[sl] = m_; sm[sl] = s_;
        }

    // cross col-half merge via LDS
    if (wc == 0 && r == 0) {
        #pragma unroll
        for (int i = 0; i < 4; ++i)
            #pragma unroll
            for (int rg = 0; rg < 4; ++rg) {
                const int p2 = wr * 64 + i * 16 + kg * 4 + rg;
                lse_m[p2] = mx[i * 4 + rg];
                lse_d[p2] = sm[i * 4 + rg];
            }
    }
    __syncthreads();
    if (wc == 1 && r == 0) {
        const float thrv = thr[0];
        #pragma unroll
        for (int i = 0; i < 4; ++i)
            #pragma unroll
            for (int rg = 0; rg < 4; ++rg) {
                const int sl = i * 4 + rg;
                const int p2 = wr * 64 + i * 16 + kg * 4 + rg;
                const float om = lse_m[p2], os = lse_d[p2];
                const float nm = fmaxf(mx[sl], om);
                const float ss = sm[sl] * __expf(mx[sl] - nm) + os * __expf(om - nm);
                out[P0 + p2] = nm + __logf(ss) - 0.5f * nrm_s[p2] - thrv;
            }
    }
}

extern "C" void kernel_launch(void* const* d_in, const int* in_sizes, int n_in,
                              void* d_out, int out_size, void* d_ws, size_t ws_size,
                              hipStream_t stream)
{
    const float* X      = (const float*)d_in[0];
    const float* center = (const float*)d_in[1];
    const float* L      = (const float*)d_in[2];
    const float* weight = (const float*)d_in[3];
    const float* thr    = (const float*)d_in[4];
    float* out = (float*)d_out;

    // ws layout: cst [256] f32 | G [18*8192] f16-as-short (~296 KB)
    float* cst = (float*)d_ws;
    short* G   = (short*)((char*)d_ws + 1024);

    gmm_prep<<<MCL, 256, 0, stream>>>(center, L, weight, G, cst);
    gmm_mfma<<<NPTS / BPTS, THREADS, 0, stream>>>(X, G, cst, thr, out);
}